// Round 4
// baseline (634.499 us; speedup 1.0000x reference)
//
#include <hip/hip_runtime.h>

// SNN "SynapticChain": B=4, T=24, N=4096, F=32, L=3 (+1 final synaptic layer).
// Wave64 = 2 rows (32 lanes/row, lane j = feature index). T-loop in kernel.
// Chain/lin matmuls: inputs are BINARY spikes -> per-block 4-bit LUT in LDS:
//   out[j] = Sum_g LUT[mat][g][nibble_g(mask)][j], bias folded into g=0.
// MLP broadcasts via per-wave LDS buffers read as float4.
// R4: 512-thread blocks (8 waves) -> 16 waves/CU (4/SIMD) for latency hiding;
//     x[t+1] prefetched under the layer chain. Math identical to R3.

namespace {
constexpr int kB = 4;
constexpr int kT = 24;
constexpr int kN = 4096;
constexpr int kF = 32;
constexpr int kNF = kN * kF;

__global__ __launch_bounds__(512, 4)
void snn_fused(const float* __restrict__ x,
               const float* __restrict__ alphas,
               const float* __restrict__ betas,
               const float* __restrict__ thrs,
               const float* __restrict__ chain_W,
               const float* __restrict__ chain_b,
               const float* __restrict__ lin_W,
               const float* __restrict__ lin_b,
               const float* __restrict__ W1,
               const float* __restrict__ b1,
               const float* __restrict__ prelu_a,
               const float* __restrict__ W2,
               const float* __restrict__ b2,
               float* __restrict__ out)
{
    const int tid  = threadIdx.x;
    const int lane = tid & 63;
    const int half = lane >> 5;        // row within the wave
    const int j    = lane & 31;        // feature / output index
    const int wid  = tid >> 6;         // wave id in block (0..7)
    const int row  = blockIdx.x * 16 + wid * 2 + half;  // 0..16383
    const int b    = row >> 12;
    const int n    = row & (kN - 1);

    // ---- LDS: nibble LUT for the 4 binary matmuls + per-wave broadcast bufs
    __shared__ float lut[4][8][16][32];   // [mat][group][nib][j]  = 64 KB
    __shared__ float s_t[8][2][32];       // transformed per row
    __shared__ float s_h[8][2][64];       // post-prelu hidden per row

    // ---- LUT init: 1024 (mat,g,j) combos, 2 per thread; 16 nibble sums each
#pragma unroll
    for (int c = 0; c < 2; ++c) {
        const int idx = tid + c * 512;
        const int mat = idx >> 8;          // 0..3
        const int g   = (idx >> 5) & 7;    // 0..7
        const int jj  = idx & 31;          // 0..31
        const float* wsrc = (mat < 3) ? (chain_W + ((mat * kF + jj) * kF + g * 4))
                                      : (lin_W + (jj * kF + g * 4));
        const float4 w = *reinterpret_cast<const float4*>(wsrc);
        const float bias = (g == 0) ? ((mat < 3) ? chain_b[mat * kF + jj] : lin_b[jj])
                                    : 0.0f;
        float s[16];
        s[0]  = 0.0f;
        s[1]  = w.x;         s[2]  = w.y;         s[3]  = w.x + w.y;
        s[4]  = w.z;         s[5]  = w.x + w.z;   s[6]  = w.y + w.z;
        s[7]  = s[3] + w.z;  s[8]  = w.w;         s[9]  = w.x + w.w;
        s[10] = w.y + w.w;   s[11] = s[3] + w.w;  s[12] = w.z + w.w;
        s[13] = s[5] + w.w;  s[14] = s[6] + w.w;  s[15] = s[7] + w.w;
#pragma unroll
        for (int nb = 0; nb < 16; ++nb) lut[mat][g][nb][jj] = s[nb] + bias;
    }
    __syncthreads();

    // ---- uniform scalars
    float al[4], be[4], th[4];
#pragma unroll
    for (int i = 0; i < 4; ++i) {
        al[i] = fminf(fmaxf(alphas[i], 0.0f), 1.0f);
        be[i] = fminf(fmaxf(betas[i],  0.0f), 1.0f);
        th[i] = thrs[i];
    }
    const float pa = prelu_a[0];

    // ---- MLP weights in registers (per-lane rows)
    float w1a[32], w1b[32];
    {
        const float4* pa4 = reinterpret_cast<const float4*>(W1 + j * kF);
        const float4* pb4 = reinterpret_cast<const float4*>(W1 + (j + 32) * kF);
#pragma unroll
        for (int q = 0; q < 8; ++q) {
            float4 va = pa4[q], vb = pb4[q];
            w1a[4*q+0] = va.x; w1a[4*q+1] = va.y; w1a[4*q+2] = va.z; w1a[4*q+3] = va.w;
            w1b[4*q+0] = vb.x; w1b[4*q+1] = vb.y; w1b[4*q+2] = vb.z; w1b[4*q+3] = vb.w;
        }
    }
    float w2r[64];
    {
        const float4* p = reinterpret_cast<const float4*>(W2 + j * 64);
#pragma unroll
        for (int q = 0; q < 16; ++q) {
            float4 v = p[q];
            w2r[4*q+0] = v.x; w2r[4*q+1] = v.y; w2r[4*q+2] = v.z; w2r[4*q+3] = v.w;
        }
    }
    const float b1a = b1[j];
    const float b1b = b1[j + 32];
    const float ob  = b2[j];

    float syn[4] = {0.f, 0.f, 0.f, 0.f};
    float mem[4] = {0.f, 0.f, 0.f, 0.f};

    const float* xp = x   + (b * kT * kN + n) * kF + j;
    float*       op = out + (b * kT * kN + n) * kF + j;

    float xv = xp[0];                      // prefetched x for current t

    for (int t = 0; t < kT; ++t) {
        // issue next-t load early; latency hides under the layer chain
        float xnext = 0.0f;
        if (t + 1 < kT) xnext = xp[(t + 1) * kNF];

        float h = xv;
        float transformed = 0.0f;

#pragma unroll
        for (int i = 0; i < 4; ++i) {
            // synaptic_step (reset from PREVIOUS mem, detached)
            const float mo    = mem[i];
            const float reset = ((mo - th[i]) > 0.0f) ? 1.0f : 0.0f;
            syn[i] = al[i] * syn[i] + h;
            mem[i] = be[i] * mem[i] + syn[i] - reset * th[i];
            const bool sp = (mem[i] - th[i]) > 0.0f;

            const unsigned long long m64 = __ballot(sp);
            const unsigned m32 = half ? (unsigned)(m64 >> 32) : (unsigned)m64;

            // binary matmul via nibble LUT (bias folded into g=0)
            float v[8];
#pragma unroll
            for (int g = 0; g < 8; ++g) {
                const unsigned nib = (m32 >> (4 * g)) & 15u;
                v[g] = lut[i][g][nib][j];
            }
            const float acc = ((v[0] + v[1]) + (v[2] + v[3]))
                            + ((v[4] + v[5]) + (v[6] + v[7]));
            if (i < 3) h = acc; else transformed = acc;
        }

        // ---- MLP: 32 -> 64 (prelu) -> 32, float4 broadcasts via per-wave LDS
        s_t[wid][half][j] = transformed;
        const float4* st4 = reinterpret_cast<const float4*>(&s_t[wid][half][0]);
        float ha0 = b1a, ha1 = 0.f, hb0 = b1b, hb1 = 0.f;
#pragma unroll
        for (int q = 0; q < 8; ++q) {
            const float4 tv = st4[q];
            if (q & 1) {
                ha1 = fmaf(tv.x, w1a[4*q+0], ha1); ha1 = fmaf(tv.y, w1a[4*q+1], ha1);
                ha1 = fmaf(tv.z, w1a[4*q+2], ha1); ha1 = fmaf(tv.w, w1a[4*q+3], ha1);
                hb1 = fmaf(tv.x, w1b[4*q+0], hb1); hb1 = fmaf(tv.y, w1b[4*q+1], hb1);
                hb1 = fmaf(tv.z, w1b[4*q+2], hb1); hb1 = fmaf(tv.w, w1b[4*q+3], hb1);
            } else {
                ha0 = fmaf(tv.x, w1a[4*q+0], ha0); ha0 = fmaf(tv.y, w1a[4*q+1], ha0);
                ha0 = fmaf(tv.z, w1a[4*q+2], ha0); ha0 = fmaf(tv.w, w1a[4*q+3], ha0);
                hb0 = fmaf(tv.x, w1b[4*q+0], hb0); hb0 = fmaf(tv.y, w1b[4*q+1], hb0);
                hb0 = fmaf(tv.z, w1b[4*q+2], hb0); hb0 = fmaf(tv.w, w1b[4*q+3], hb0);
            }
        }
        const float h1a = ha0 + ha1;
        const float h1b = hb0 + hb1;
        const float g1 = (h1a > 0.0f) ? h1a : pa * h1a;
        const float g2 = (h1b > 0.0f) ? h1b : pa * h1b;

        s_h[wid][half][j]      = g1;
        s_h[wid][half][j + 32] = g2;
        const float4* sh4 = reinterpret_cast<const float4*>(&s_h[wid][half][0]);
        float o0 = ob, o1 = 0.f, o2 = 0.f, o3 = 0.f;
#pragma unroll
        for (int q = 0; q < 16; ++q) {
            const float4 hv = sh4[q];
            switch (q & 3) {
            case 0:
                o0 = fmaf(hv.x, w2r[4*q+0], o0); o0 = fmaf(hv.y, w2r[4*q+1], o0);
                o0 = fmaf(hv.z, w2r[4*q+2], o0); o0 = fmaf(hv.w, w2r[4*q+3], o0);
                break;
            case 1:
                o1 = fmaf(hv.x, w2r[4*q+0], o1); o1 = fmaf(hv.y, w2r[4*q+1], o1);
                o1 = fmaf(hv.z, w2r[4*q+2], o1); o1 = fmaf(hv.w, w2r[4*q+3], o1);
                break;
            case 2:
                o2 = fmaf(hv.x, w2r[4*q+0], o2); o2 = fmaf(hv.y, w2r[4*q+1], o2);
                o2 = fmaf(hv.z, w2r[4*q+2], o2); o2 = fmaf(hv.w, w2r[4*q+3], o2);
                break;
            default:
                o3 = fmaf(hv.x, w2r[4*q+0], o3); o3 = fmaf(hv.y, w2r[4*q+1], o3);
                o3 = fmaf(hv.z, w2r[4*q+2], o3); o3 = fmaf(hv.w, w2r[4*q+3], o3);
                break;
            }
        }
        op[t * kNF] = (o0 + o1) + (o2 + o3);
        xv = xnext;
    }
}
} // namespace

extern "C" void kernel_launch(void* const* d_in, const int* in_sizes, int n_in,
                              void* d_out, int out_size, void* d_ws, size_t ws_size,
                              hipStream_t stream) {
    const float* x        = (const float*)d_in[0];
    const float* alphas   = (const float*)d_in[1];
    const float* betas    = (const float*)d_in[2];
    const float* thrs     = (const float*)d_in[3];
    const float* chain_W  = (const float*)d_in[4];
    const float* chain_b  = (const float*)d_in[5];
    const float* lin_W    = (const float*)d_in[6];
    const float* lin_b    = (const float*)d_in[7];
    const float* W1       = (const float*)d_in[8];
    const float* b1       = (const float*)d_in[9];
    const float* prelu_a  = (const float*)d_in[10];
    const float* W2       = (const float*)d_in[11];
    const float* b2       = (const float*)d_in[12];
    float* out            = (float*)d_out;

    const int rows   = kB * kN;          // 16384
    const int blocks = rows / 16;        // 1024 blocks * 8 waves * 2 rows/wave
    hipLaunchKernelGGL(snn_fused, dim3(blocks), dim3(512), 0, stream,
                       x, alphas, betas, thrs, chain_W, chain_b, lin_W, lin_b,
                       W1, b1, prelu_a, W2, b2, out);
}

// Round 5
// 157.853 us; speedup vs baseline: 4.0196x; 4.0196x over previous
//
#include <hip/hip_runtime.h>

// SNN "SynapticChain": B=4, T=24, N=4096, F=32, L=3 (+1 final synaptic layer).
// Wave64 = 2 rows (32 lanes/row, lane j = feature index). T-loop in kernel.
// Chain/lin matmuls: inputs are BINARY spikes -> per-block 4-bit LUT in LDS:
//   out[j] = Sum_g LUT[mat][g][nibble_g(mask)][j], bias folded into g=0.
// MLP broadcasts via per-wave LDS buffers read as float4.
// R5: 512-thread blocks, __launch_bounds__(512,2) -- R4's (512,4) capped VGPR
//     at 64 and spilled ~2.2 GB to scratch (FETCH 24.7MB->2.0GB). Cap >=128
//     fits the ~120-VGPR demand; LDS 70KB -> 2 blocks/CU -> 4 waves/SIMD.

namespace {
constexpr int kB = 4;
constexpr int kT = 24;
constexpr int kN = 4096;
constexpr int kF = 32;
constexpr int kNF = kN * kF;

__global__ __launch_bounds__(512, 2)
void snn_fused(const float* __restrict__ x,
               const float* __restrict__ alphas,
               const float* __restrict__ betas,
               const float* __restrict__ thrs,
               const float* __restrict__ chain_W,
               const float* __restrict__ chain_b,
               const float* __restrict__ lin_W,
               const float* __restrict__ lin_b,
               const float* __restrict__ W1,
               const float* __restrict__ b1,
               const float* __restrict__ prelu_a,
               const float* __restrict__ W2,
               const float* __restrict__ b2,
               float* __restrict__ out)
{
    const int tid  = threadIdx.x;
    const int lane = tid & 63;
    const int half = lane >> 5;        // row within the wave
    const int j    = lane & 31;        // feature / output index
    const int wid  = tid >> 6;         // wave id in block (0..7)
    const int row  = blockIdx.x * 16 + wid * 2 + half;  // 0..16383
    const int b    = row >> 12;
    const int n    = row & (kN - 1);

    // ---- LDS: nibble LUT for the 4 binary matmuls + per-wave broadcast bufs
    __shared__ float lut[4][8][16][32];   // [mat][group][nib][j]  = 64 KB
    __shared__ float s_t[8][2][32];       // transformed per row
    __shared__ float s_h[8][2][64];       // post-prelu hidden per row

    // ---- LUT init: 1024 (mat,g,j) combos, 2 per thread; 16 nibble sums each
#pragma unroll
    for (int c = 0; c < 2; ++c) {
        const int idx = tid + c * 512;
        const int mat = idx >> 8;          // 0..3
        const int g   = (idx >> 5) & 7;    // 0..7
        const int jj  = idx & 31;          // 0..31
        const float* wsrc = (mat < 3) ? (chain_W + ((mat * kF + jj) * kF + g * 4))
                                      : (lin_W + (jj * kF + g * 4));
        const float4 w = *reinterpret_cast<const float4*>(wsrc);
        const float bias = (g == 0) ? ((mat < 3) ? chain_b[mat * kF + jj] : lin_b[jj])
                                    : 0.0f;
        float s[16];
        s[0]  = 0.0f;
        s[1]  = w.x;         s[2]  = w.y;         s[3]  = w.x + w.y;
        s[4]  = w.z;         s[5]  = w.x + w.z;   s[6]  = w.y + w.z;
        s[7]  = s[3] + w.z;  s[8]  = w.w;         s[9]  = w.x + w.w;
        s[10] = w.y + w.w;   s[11] = s[3] + w.w;  s[12] = w.z + w.w;
        s[13] = s[5] + w.w;  s[14] = s[6] + w.w;  s[15] = s[7] + w.w;
#pragma unroll
        for (int nb = 0; nb < 16; ++nb) lut[mat][g][nb][jj] = s[nb] + bias;
    }
    __syncthreads();

    // ---- uniform scalars
    float al[4], be[4], th[4];
#pragma unroll
    for (int i = 0; i < 4; ++i) {
        al[i] = fminf(fmaxf(alphas[i], 0.0f), 1.0f);
        be[i] = fminf(fmaxf(betas[i],  0.0f), 1.0f);
        th[i] = thrs[i];
    }
    const float pa = prelu_a[0];

    // ---- MLP weights in registers (per-lane rows)
    float w1a[32], w1b[32];
    {
        const float4* pa4 = reinterpret_cast<const float4*>(W1 + j * kF);
        const float4* pb4 = reinterpret_cast<const float4*>(W1 + (j + 32) * kF);
#pragma unroll
        for (int q = 0; q < 8; ++q) {
            float4 va = pa4[q], vb = pb4[q];
            w1a[4*q+0] = va.x; w1a[4*q+1] = va.y; w1a[4*q+2] = va.z; w1a[4*q+3] = va.w;
            w1b[4*q+0] = vb.x; w1b[4*q+1] = vb.y; w1b[4*q+2] = vb.z; w1b[4*q+3] = vb.w;
        }
    }
    float w2r[64];
    {
        const float4* p = reinterpret_cast<const float4*>(W2 + j * 64);
#pragma unroll
        for (int q = 0; q < 16; ++q) {
            float4 v = p[q];
            w2r[4*q+0] = v.x; w2r[4*q+1] = v.y; w2r[4*q+2] = v.z; w2r[4*q+3] = v.w;
        }
    }
    const float b1a = b1[j];
    const float b1b = b1[j + 32];
    const float ob  = b2[j];

    float syn[4] = {0.f, 0.f, 0.f, 0.f};
    float mem[4] = {0.f, 0.f, 0.f, 0.f};

    const float* xp = x   + (b * kT * kN + n) * kF + j;
    float*       op = out + (b * kT * kN + n) * kF + j;

    float xv = xp[0];                      // prefetched x for current t

    for (int t = 0; t < kT; ++t) {
        // issue next-t load early; latency hides under the layer chain
        float xnext = 0.0f;
        if (t + 1 < kT) xnext = xp[(t + 1) * kNF];

        float h = xv;
        float transformed = 0.0f;

#pragma unroll
        for (int i = 0; i < 4; ++i) {
            // synaptic_step (reset from PREVIOUS mem, detached)
            const float mo    = mem[i];
            const float reset = ((mo - th[i]) > 0.0f) ? 1.0f : 0.0f;
            syn[i] = al[i] * syn[i] + h;
            mem[i] = be[i] * mem[i] + syn[i] - reset * th[i];
            const bool sp = (mem[i] - th[i]) > 0.0f;

            const unsigned long long m64 = __ballot(sp);
            const unsigned m32 = half ? (unsigned)(m64 >> 32) : (unsigned)m64;

            // binary matmul via nibble LUT (bias folded into g=0)
            float v[8];
#pragma unroll
            for (int g = 0; g < 8; ++g) {
                const unsigned nib = (m32 >> (4 * g)) & 15u;
                v[g] = lut[i][g][nib][j];
            }
            const float acc = ((v[0] + v[1]) + (v[2] + v[3]))
                            + ((v[4] + v[5]) + (v[6] + v[7]));
            if (i < 3) h = acc; else transformed = acc;
        }

        // ---- MLP: 32 -> 64 (prelu) -> 32, float4 broadcasts via per-wave LDS
        s_t[wid][half][j] = transformed;
        const float4* st4 = reinterpret_cast<const float4*>(&s_t[wid][half][0]);
        float ha0 = b1a, ha1 = 0.f, hb0 = b1b, hb1 = 0.f;
#pragma unroll
        for (int q = 0; q < 8; ++q) {
            const float4 tv = st4[q];
            if (q & 1) {
                ha1 = fmaf(tv.x, w1a[4*q+0], ha1); ha1 = fmaf(tv.y, w1a[4*q+1], ha1);
                ha1 = fmaf(tv.z, w1a[4*q+2], ha1); ha1 = fmaf(tv.w, w1a[4*q+3], ha1);
                hb1 = fmaf(tv.x, w1b[4*q+0], hb1); hb1 = fmaf(tv.y, w1b[4*q+1], hb1);
                hb1 = fmaf(tv.z, w1b[4*q+2], hb1); hb1 = fmaf(tv.w, w1b[4*q+3], hb1);
            } else {
                ha0 = fmaf(tv.x, w1a[4*q+0], ha0); ha0 = fmaf(tv.y, w1a[4*q+1], ha0);
                ha0 = fmaf(tv.z, w1a[4*q+2], ha0); ha0 = fmaf(tv.w, w1a[4*q+3], ha0);
                hb0 = fmaf(tv.x, w1b[4*q+0], hb0); hb0 = fmaf(tv.y, w1b[4*q+1], hb0);
                hb0 = fmaf(tv.z, w1b[4*q+2], hb0); hb0 = fmaf(tv.w, w1b[4*q+3], hb0);
            }
        }
        const float h1a = ha0 + ha1;
        const float h1b = hb0 + hb1;
        const float g1 = (h1a > 0.0f) ? h1a : pa * h1a;
        const float g2 = (h1b > 0.0f) ? h1b : pa * h1b;

        s_h[wid][half][j]      = g1;
        s_h[wid][half][j + 32] = g2;
        const float4* sh4 = reinterpret_cast<const float4*>(&s_h[wid][half][0]);
        float o0 = ob, o1 = 0.f, o2 = 0.f, o3 = 0.f;
#pragma unroll
        for (int q = 0; q < 16; ++q) {
            const float4 hv = sh4[q];
            switch (q & 3) {
            case 0:
                o0 = fmaf(hv.x, w2r[4*q+0], o0); o0 = fmaf(hv.y, w2r[4*q+1], o0);
                o0 = fmaf(hv.z, w2r[4*q+2], o0); o0 = fmaf(hv.w, w2r[4*q+3], o0);
                break;
            case 1:
                o1 = fmaf(hv.x, w2r[4*q+0], o1); o1 = fmaf(hv.y, w2r[4*q+1], o1);
                o1 = fmaf(hv.z, w2r[4*q+2], o1); o1 = fmaf(hv.w, w2r[4*q+3], o1);
                break;
            case 2:
                o2 = fmaf(hv.x, w2r[4*q+0], o2); o2 = fmaf(hv.y, w2r[4*q+1], o2);
                o2 = fmaf(hv.z, w2r[4*q+2], o2); o2 = fmaf(hv.w, w2r[4*q+3], o2);
                break;
            default:
                o3 = fmaf(hv.x, w2r[4*q+0], o3); o3 = fmaf(hv.y, w2r[4*q+1], o3);
                o3 = fmaf(hv.z, w2r[4*q+2], o3); o3 = fmaf(hv.w, w2r[4*q+3], o3);
                break;
            }
        }
        op[t * kNF] = (o0 + o1) + (o2 + o3);
        xv = xnext;
    }
}
} // namespace

extern "C" void kernel_launch(void* const* d_in, const int* in_sizes, int n_in,
                              void* d_out, int out_size, void* d_ws, size_t ws_size,
                              hipStream_t stream) {
    const float* x        = (const float*)d_in[0];
    const float* alphas   = (const float*)d_in[1];
    const float* betas    = (const float*)d_in[2];
    const float* thrs     = (const float*)d_in[3];
    const float* chain_W  = (const float*)d_in[4];
    const float* chain_b  = (const float*)d_in[5];
    const float* lin_W    = (const float*)d_in[6];
    const float* lin_b    = (const float*)d_in[7];
    const float* W1       = (const float*)d_in[8];
    const float* b1       = (const float*)d_in[9];
    const float* prelu_a  = (const float*)d_in[10];
    const float* W2       = (const float*)d_in[11];
    const float* b2       = (const float*)d_in[12];
    float* out            = (float*)d_out;

    const int rows   = kB * kN;          // 16384
    const int blocks = rows / 16;        // 1024 blocks * 8 waves * 2 rows/wave
    hipLaunchKernelGGL(snn_fused, dim3(blocks), dim3(512), 0, stream,
                       x, alphas, betas, thrs, chain_W, chain_b, lin_W, lin_b,
                       W1, b1, prelu_a, W2, b2, out);
}